// Round 6
// baseline (243.643 us; speedup 1.0000x reference)
//
#include <hip/hip_runtime.h>
#include <math.h>

#define NN 20000
#define NE 640000

typedef __attribute__((ext_vector_type(8))) short short8v;
typedef __attribute__((ext_vector_type(4))) float f32x4;

__device__ inline unsigned short f2bf(float f) {
    unsigned int u = __builtin_bit_cast(unsigned int, f);
    u += 0x7fff + ((u >> 16) & 1);   // RNE
    return (unsigned short)(u >> 16);
}
__device__ inline float bf2f(unsigned short s) {
    unsigned int u = ((unsigned int)s) << 16;
    return __builtin_bit_cast(float, u);
}
// async global->LDS, 16B per lane; dest = uniform base + lane*16
__device__ inline void gload16(const unsigned short* g, short* l) {
    __builtin_amdgcn_global_load_lds(
        (const __attribute__((address_space(1))) unsigned int*)g,
        (__attribute__((address_space(3))) unsigned int*)l, 16, 0, 0);
}

// ---- prep: Wbig pack (+W_dec fold), bias_cat, cbits zero, Whl bf16 hi/lo ----
__global__ __launch_bounds__(256)
void prep_kernel(const float* __restrict__ W_ih, const float* __restrict__ W_hh,
                 const float* __restrict__ W_dec, const float* __restrict__ W_enc,
                 const float* __restrict__ b_ih, const float* __restrict__ b_hh,
                 const float* __restrict__ b_dec,
                 unsigned short* __restrict__ Wbig, float* __restrict__ bias_cat,
                 unsigned int* __restrict__ cbits, unsigned short* __restrict__ Whl)
{
    int r = blockIdx.x;              // 1024
    int tid = threadIdx.x;
    int zi = r * 256 + tid;
    if (zi < NN * 4) cbits[zi] = 0u;
    if (r < 128) {                   // Whl: hi/lo planes of W_enc row r
        for (int k2 = tid; k2 < 512; k2 += 256) {
            float v = W_enc[(size_t)r * 512 + k2];
            unsigned short hi = f2bf(v);
            Whl[(size_t)r * 512 + k2] = hi;
            Whl[65536 + (size_t)r * 512 + k2] = f2bf(v - bf2f(hi));
        }
    }
    int g = r >> 8, j = r & 255;
    for (int k = tid; k < 512; k += 256) {
        float v;
        if (k < 256) {
            v = (g < 3) ? W_ih[(size_t)(g * 256 + j) * 384 + k] : 0.f;
        } else {
            int sr = (g < 2) ? g * 256 + j : 512 + j;
            v = (g == 2) ? 0.f : W_hh[(size_t)sr * 256 + (k - 256)];
        }
        Wbig[(size_t)r * 640 + k] = f2bf(v);
    }
    if (tid < 128) {                 // c-cols: (W_ih[:,256:] @ W_dec)[r][tid]
        float acc = 0.f;
        if (g < 3) {
            const float* wr = W_ih + (size_t)(g * 256 + j) * 384 + 256;
#pragma unroll 4
            for (int p = 0; p < 128; ++p) acc += wr[p] * W_dec[p * 128 + tid];
        }
        Wbig[(size_t)r * 640 + 512 + tid] = f2bf(acc);
    } else if (tid == 128) {
        float v;
        if (g == 3) {
            v = b_hh[512 + j];
        } else {
            int sr = g * 256 + j;
            float bdt = 0.f;
            for (int m = 0; m < 128; ++m) bdt += W_ih[(size_t)sr * 384 + 256 + m] * b_dec[m];
            v = b_ih[sr] + bdt + ((g < 2) ? b_hh[sr] : 0.f);
        }
        bias_cat[r] = v;
    }
}

// ---- enc: L = [x|h] @ W_enc^T + b_enc, bf16x3; side-writes Abig[:,0:512] hi ----
// A tiles padded [64][72]; W tiles linear-64 + XOR swizzle (from precomputed Whl).
__global__ __launch_bounds__(256)
void enc_gemm(const float* __restrict__ x, const float* __restrict__ h,
              const unsigned short* __restrict__ Whl, const float* __restrict__ b_enc,
              float* __restrict__ L, unsigned short* __restrict__ Abig)
{
    __shared__ __align__(16) short Ah[64][72], Al[64][72];
    __shared__ __align__(16) short Wh[128 * 64], Wl[128 * 64];
    const int bm0 = blockIdx.x * 64;
    const int tid = threadIdx.x;
    const int lane = tid & 63;
    const int wave = tid >> 6;
    const int wm = wave >> 1, wn = wave & 1;   // wave: 32 rows x 64 cols
    const int r16 = lane & 15, kg = lane >> 4;
    const int sw = r16 & 7;

    f32x4 acc[2][4];
#pragma unroll
    for (int i = 0; i < 2; ++i)
#pragma unroll
        for (int j = 0; j < 4; ++j) acc[i][j] = (f32x4){0.f, 0.f, 0.f, 0.f};

    for (int kt = 0; kt < 512; kt += 64) {
#pragma unroll
        for (int it = 0; it < 2; ++it) {        // A: 64 rows x 8 segs, cvt hi/lo
            int seg = tid + it * 256;
            int row = seg >> 3, s = seg & 7;
            int kc = kt + s * 8;
            int gm = bm0 + row; if (gm >= NN) gm = NN - 1;
            const float* p = (kc < 256) ? (x + (size_t)gm * 256 + kc)
                                        : (h + (size_t)gm * 256 + (kc - 256));
            float4 v0 = *(const float4*)p;
            float4 v1 = *(const float4*)(p + 4);
            float vv[8] = {v0.x, v0.y, v0.z, v0.w, v1.x, v1.y, v1.z, v1.w};
            short8v hi, lo;
#pragma unroll
            for (int t = 0; t < 8; ++t) {
                unsigned short hb = f2bf(vv[t]);
                hi[t] = (short)hb;
                lo[t] = (short)f2bf(vv[t] - bf2f(hb));
            }
            *(short8v*)&Ah[row][s * 8] = hi;
            *(short8v*)&Al[row][s * 8] = lo;
            *(short8v*)&Abig[(size_t)gm * 640 + kc] = hi;
        }
#pragma unroll
        for (int it = 0; it < 4; ++it) {        // W: copy, XOR-swizzled store
            int seg = tid + it * 256;
            int row = seg >> 3, s = seg & 7;
            size_t off = (size_t)row * 512 + kt + s * 8;
            int p = (s ^ (row & 7)) * 8;
            *(short8v*)&Wh[row * 64 + p] = *(const short8v*)&Whl[off];
            *(short8v*)&Wl[row * 64 + p] = *(const short8v*)&Whl[65536 + off];
        }
        __syncthreads();
#pragma unroll
        for (int ks = 0; ks < 2; ++ks) {
            int kc = ks * 32 + kg * 8;
            int gsel = (ks * 4 + kg) ^ sw;
            short8v ah[2], al[2], wh[4], wl[4];
#pragma unroll
            for (int f = 0; f < 2; ++f) {
                ah[f] = *(const short8v*)&Ah[wm * 32 + f * 16 + r16][kc];
                al[f] = *(const short8v*)&Al[wm * 32 + f * 16 + r16][kc];
            }
#pragma unroll
            for (int f = 0; f < 4; ++f) {
                int wrow = wn * 64 + f * 16 + r16;
                wh[f] = *(const short8v*)&Wh[wrow * 64 + gsel * 8];
                wl[f] = *(const short8v*)&Wl[wrow * 64 + gsel * 8];
            }
#pragma unroll
            for (int fi = 0; fi < 2; ++fi)
#pragma unroll
                for (int fj = 0; fj < 4; ++fj) {
                    acc[fi][fj] = __builtin_amdgcn_mfma_f32_16x16x32_bf16(
                        ah[fi], wh[fj], acc[fi][fj], 0, 0, 0);
                    acc[fi][fj] = __builtin_amdgcn_mfma_f32_16x16x32_bf16(
                        al[fi], wh[fj], acc[fi][fj], 0, 0, 0);
                    acc[fi][fj] = __builtin_amdgcn_mfma_f32_16x16x32_bf16(
                        ah[fi], wl[fj], acc[fi][fj], 0, 0, 0);
                }
        }
        __syncthreads();
    }
#pragma unroll
    for (int fi = 0; fi < 2; ++fi) {
        int rg = bm0 + wm * 32 + fi * 16 + kg * 4;
#pragma unroll
        for (int fj = 0; fj < 4; ++fj) {
            int cg = wn * 64 + fj * 16 + r16;
            float bv = b_enc[cg];
#pragma unroll
            for (int i = 0; i < 4; ++i)
                if (rg + i < NN) L[(size_t)(rg + i) * 128 + cg] = acc[fi][fj][i] + bv;
        }
    }
}

// ---- edge: per-edge gumbel argmax -> OR into cbits ----
__global__ __launch_bounds__(256)
void edge_msg_kernel(const float* __restrict__ L, const float* __restrict__ gumbel,
                     const int* __restrict__ src, const int* __restrict__ dst,
                     unsigned int* __restrict__ cbits, int E)
{
    int lane = threadIdx.x & 63;
    int slot = blockIdx.x * 4 + (threadIdx.x >> 6);
    int nslots = gridDim.x * 4;
    for (int e = slot; e < E; e += nslots) {
        int s = src[e];
        float2 g = *(const float2*)&gumbel[(size_t)e * 128 + lane * 2];
        float2 l = *(const float2*)&L[(size_t)s * 128 + lane * 2];
        int choice1 = (l.x + g.x) < (l.y + g.y) ? 1 : 0;
        unsigned int val = 1u << (2 * (lane & 15) + choice1);
        val |= __shfl_xor(val, 1);
        val |= __shfl_xor(val, 2);
        val |= __shfl_xor(val, 4);
        val |= __shfl_xor(val, 8);
        if ((lane & 15) == 0) {
            int d = dst[e];
            atomicOr(&cbits[(size_t)d * 4 + (lane >> 4)], val);
        }
    }
}

// ---- expand cbits -> Abig[:,512:640] bf16 0/1 ----
__global__ __launch_bounds__(256)
void expand_c(const unsigned int* __restrict__ cbits, unsigned short* __restrict__ Abig)
{
    int idx = blockIdx.x * 256 + threadIdx.x;   // NN*4
    if (idx >= NN * 4) return;
    int n = idx >> 2, w = idx & 3;
    unsigned int bits = cbits[idx];
    unsigned short* p = Abig + (size_t)n * 640 + 512 + w * 32;
#pragma unroll
    for (int t = 0; t < 32; t += 8) {
        short8v v;
#pragma unroll
        for (int u = 0; u < 8; ++u)
            v[u] = ((bits >> (t + u)) & 1u) ? (short)0x3F80 : (short)0;
        *(short8v*)&p[t] = v;
    }
}

// ---- fused gates GEMM + GRU, double-buffered with counted vmcnt ----
// Block: 64 rows x 64 hidden cols, 4 gates (3 active/phase). Wave w: cols [16w,16w+16).
// K layout [x(0:256)|h(256:512)|c(512:640)]. Ws stages only the 3 active gate slabs.
__global__ __launch_bounds__(256)
void gates_gru(const unsigned short* __restrict__ Abig,
               const unsigned short* __restrict__ Wbig,
               const float* __restrict__ bias_cat,
               const float* __restrict__ h, float* __restrict__ out)
{
    __shared__ __align__(16) short As[2][64 * 64];    // 2 x 8 KB
    __shared__ __align__(16) short Ws[2][192 * 64];   // 2 x 24 KB
    const int bm0 = blockIdx.x * 64;
    const int j0  = blockIdx.y * 64;
    const int tid = threadIdx.x;
    const int lane = tid & 63;
    const int w = tid >> 6;
    const int r16 = lane & 15, kg = lane >> 4;
    const int sw = r16 & 7;

    f32x4 acc[4][4];
#pragma unroll
    for (int g = 0; g < 4; ++g)
#pragma unroll
        for (int i = 0; i < 4; ++i) acc[g][i] = (f32x4){0.f, 0.f, 0.f, 0.f};

    // stage kt's tiles into buffer b: 2 As-loads + 6 Ws-loads per wave = 8 vmem ops
    auto STAGE = [&](int b, int kt) {
        const int kc0 = kt * 64;
        const int g2 = (kt < 4 || kt >= 8) ? 2 : 3;   // slot2 gate
#pragma unroll
        for (int it = 0; it < 2; ++it) {
            int chunk = w * 2 + it;
            int slot = chunk * 64 + lane;
            int row = slot >> 3, gch = slot & 7;
            int gm = bm0 + row; if (gm >= NN) gm = NN - 1;
            gload16(Abig + (size_t)gm * 640 + kc0 + ((gch ^ (row & 7)) << 3),
                    As[b] + chunk * 512);
        }
#pragma unroll
        for (int it = 0; it < 6; ++it) {
            int chunk = w * 6 + it;
            int slot = chunk * 64 + lane;
            int row = slot >> 3, gch = slot & 7;       // row 0..191
            int srow = row >> 6;                        // slot 0..2
            int gate = (srow < 2) ? srow : g2;
            int wr = gate * 256 + j0 + (row & 63);
            gload16(Wbig + (size_t)wr * 640 + kc0 + ((gch ^ (row & 7)) << 3),
                    Ws[b] + chunk * 512);
        }
    };

    STAGE(0, 0);
#pragma unroll
    for (int kt = 0; kt < 10; ++kt) {
        const int cur = kt & 1;
        if (kt < 9) {
            STAGE(cur ^ 1, kt + 1);
            asm volatile("s_waitcnt vmcnt(8)" ::: "memory");
        } else {
            asm volatile("s_waitcnt vmcnt(0)" ::: "memory");
        }
        __builtin_amdgcn_s_barrier();
        __builtin_amdgcn_sched_barrier(0);
        const int g2c = (kt < 4 || kt >= 8) ? 2 : 3;
        __builtin_amdgcn_s_setprio(1);
#pragma unroll
        for (int ks = 0; ks < 2; ++ks) {
            int gsel = (ks * 4 + kg) ^ sw;
            short8v a[4];
#pragma unroll
            for (int fi = 0; fi < 4; ++fi)
                a[fi] = *(const short8v*)&As[cur][(fi * 16 + r16) * 64 + gsel * 8];
#pragma unroll
            for (int s = 0; s < 3; ++s) {
                short8v b = *(const short8v*)&Ws[cur][(s * 64 + w * 16 + r16) * 64 + gsel * 8];
                int gate = (s < 2) ? s : g2c;
#pragma unroll
                for (int fi = 0; fi < 4; ++fi)
                    acc[gate][fi] = __builtin_amdgcn_mfma_f32_16x16x32_bf16(
                        a[fi], b, acc[gate][fi], 0, 0, 0);
            }
        }
        __builtin_amdgcn_s_setprio(0);
        __builtin_amdgcn_sched_barrier(0);
        __builtin_amdgcn_s_barrier();
    }
    // GRU epilogue: row = bm0 + fi*16 + kg*4 + i, col = j0 + w*16 + r16
    const int cg = j0 + w * 16 + r16;
    const float br = bias_cat[cg],       bz = bias_cat[256 + cg];
    const float bi = bias_cat[512 + cg], bh = bias_cat[768 + cg];
#pragma unroll
    for (int fi = 0; fi < 4; ++fi) {
        int rg = bm0 + fi * 16 + kg * 4;
#pragma unroll
        for (int i = 0; i < 4; ++i) {
            int m = rg + i;
            if (m >= NN) continue;
            float rp = acc[0][fi][i] + br;
            float zp = acc[1][fi][i] + bz;
            float ip = acc[2][fi][i] + bi;
            float hp = acc[3][fi][i] + bh;
            float hv = h[(size_t)m * 256 + cg];
            float r = 1.f / (1.f + __expf(-rp));
            float z = 1.f / (1.f + __expf(-zp));
            float nn2 = tanhf(ip + r * hp);
            out[(size_t)m * 256 + cg] = (1.f - z) * nn2 + z * hv;
        }
    }
}

extern "C" void kernel_launch(void* const* d_in, const int* in_sizes, int n_in,
                              void* d_out, int out_size, void* d_ws, size_t ws_size,
                              hipStream_t stream)
{
    const float* x     = (const float*)d_in[0];
    const float* h     = (const float*)d_in[1];
    const float* W_enc = (const float*)d_in[2];
    const float* b_enc = (const float*)d_in[3];
    const float* W_dec = (const float*)d_in[4];
    const float* b_dec = (const float*)d_in[5];
    const float* W_ih  = (const float*)d_in[6];
    const float* b_ih  = (const float*)d_in[7];
    const float* W_hh  = (const float*)d_in[8];
    const float* b_hh  = (const float*)d_in[9];
    const float* gumbel = (const float*)d_in[10];
    const int*   src   = (const int*)d_in[11];
    const int*   dst   = (const int*)d_in[12];
    float* out = (float*)d_out;

    char* ws = (char*)d_ws;
    float*          L        = (float*)(ws);                       // 10,240,000
    unsigned int*   cbits    = (unsigned int*)(ws + 10240000);     //    320,000
    unsigned short* Wbig     = (unsigned short*)(ws + 10560000);   //  1,310,720
    float*          bias_cat = (float*)(ws + 11870720);            //      4,096
    unsigned short* Whl      = (unsigned short*)(ws + 11874816);   //    262,144
    unsigned short* Abig     = (unsigned short*)(ws + 12136960);   // 25,600,000

    prep_kernel<<<1024, 256, 0, stream>>>(W_ih, W_hh, W_dec, W_enc, b_ih, b_hh, b_dec,
                                          Wbig, bias_cat, cbits, Whl);
    enc_gemm<<<313, 256, 0, stream>>>(x, h, Whl, b_enc, L, Abig);
    edge_msg_kernel<<<2048, 256, 0, stream>>>(L, gumbel, src, dst, cbits, NE);
    expand_c<<<(NN * 4 + 255) / 256, 256, 0, stream>>>(cbits, Abig);
    gates_gru<<<dim3(313, 4), 256, 0, stream>>>(Abig, Wbig, bias_cat, h, out);
}

// Round 7
// 237.034 us; speedup vs baseline: 1.0279x; 1.0279x over previous
//
#include <hip/hip_runtime.h>
#include <math.h>

#define NN 20000
#define NE 640000

typedef __attribute__((ext_vector_type(8))) short short8v;
typedef __attribute__((ext_vector_type(4))) float f32x4;

__device__ inline unsigned short f2bf(float f) {
    unsigned int u = __builtin_bit_cast(unsigned int, f);
    u += 0x7fff + ((u >> 16) & 1);   // RNE
    return (unsigned short)(u >> 16);
}
__device__ inline float bf2f(unsigned short s) {
    unsigned int u = ((unsigned int)s) << 16;
    return __builtin_bit_cast(float, u);
}
// async global->LDS, 16B per lane; dest = uniform base + lane*16
__device__ inline void gload16(const unsigned short* g, short* l) {
    __builtin_amdgcn_global_load_lds(
        (const __attribute__((address_space(1))) unsigned int*)g,
        (__attribute__((address_space(3))) unsigned int*)l, 16, 0, 0);
}

// ---- prep: Wbig pack (+W_dec fold), bias_cat, cbits zero, Whl bf16 hi/lo ----
__global__ __launch_bounds__(256)
void prep_kernel(const float* __restrict__ W_ih, const float* __restrict__ W_hh,
                 const float* __restrict__ W_dec, const float* __restrict__ W_enc,
                 const float* __restrict__ b_ih, const float* __restrict__ b_hh,
                 const float* __restrict__ b_dec,
                 unsigned short* __restrict__ Wbig, float* __restrict__ bias_cat,
                 unsigned int* __restrict__ cbits, unsigned short* __restrict__ Whl)
{
    int r = blockIdx.x;              // 1024
    int tid = threadIdx.x;
    int zi = r * 256 + tid;
    if (zi < NN * 4) cbits[zi] = 0u;
    if (r < 128) {                   // Whl: hi/lo planes of W_enc row r
        for (int k2 = tid; k2 < 512; k2 += 256) {
            float v = W_enc[(size_t)r * 512 + k2];
            unsigned short hi = f2bf(v);
            Whl[(size_t)r * 512 + k2] = hi;
            Whl[65536 + (size_t)r * 512 + k2] = f2bf(v - bf2f(hi));
        }
    }
    int g = r >> 8, j = r & 255;
    for (int k = tid; k < 512; k += 256) {
        float v;
        if (k < 256) {
            v = (g < 3) ? W_ih[(size_t)(g * 256 + j) * 384 + k] : 0.f;
        } else {
            int sr = (g < 2) ? g * 256 + j : 512 + j;
            v = (g == 2) ? 0.f : W_hh[(size_t)sr * 256 + (k - 256)];
        }
        Wbig[(size_t)r * 640 + k] = f2bf(v);
    }
    if (tid < 128) {                 // c-cols: (W_ih[:,256:] @ W_dec)[r][tid]
        float acc = 0.f;
        if (g < 3) {
            const float* wr = W_ih + (size_t)(g * 256 + j) * 384 + 256;
#pragma unroll 4
            for (int p = 0; p < 128; ++p) acc += wr[p] * W_dec[p * 128 + tid];
        }
        Wbig[(size_t)r * 640 + 512 + tid] = f2bf(acc);
    } else if (tid == 128) {
        float v;
        if (g == 3) {
            v = b_hh[512 + j];
        } else {
            int sr = g * 256 + j;
            float bdt = 0.f;
            for (int m = 0; m < 128; ++m) bdt += W_ih[(size_t)sr * 384 + 256 + m] * b_dec[m];
            v = b_ih[sr] + bdt + ((g < 2) ? b_hh[sr] : 0.f);
        }
        bias_cat[r] = v;
    }
}

// ---- enc v3: 8 waves, reg-prefetch pipeline, bf16x3; emits Ldiff + Abig hi ----
// Ldiff[n][j] = logit(n,2j) - logit(n,2j+1)  (incl. b_enc diff)
__global__ __launch_bounds__(512)
void enc_gemm(const float* __restrict__ x, const float* __restrict__ h,
              const unsigned short* __restrict__ Whl, const float* __restrict__ b_enc,
              float* __restrict__ Ldiff, unsigned short* __restrict__ Abig)
{
    __shared__ __align__(16) short Ah[64][72], Al[64][72];
    __shared__ __align__(16) short Wh[128 * 64], Wl[128 * 64];
    const int bm0 = blockIdx.x * 64;
    const int tid = threadIdx.x;       // 0..511
    const int lane = tid & 63;
    const int wave = tid >> 6;
    const int wm = wave >> 2, wn = wave & 3;   // wave: 32 rows x 32 cols
    const int r16 = lane & 15, kg = lane >> 4;
    const int sw = r16 & 7;

    // fixed staging coords
    const int arow = tid >> 3, as_ = tid & 7;          // A: 64 rows x 8 segs
    const int agm = (bm0 + arow >= NN) ? NN - 1 : bm0 + arow;
    const int wrow0 = tid >> 3, wrow1 = (tid >> 3) + 64, ws_ = tid & 7;

    f32x4 acc[2][2];
#pragma unroll
    for (int i = 0; i < 2; ++i)
#pragma unroll
        for (int j = 0; j < 2; ++j) acc[i][j] = (f32x4){0.f, 0.f, 0.f, 0.f};

    float4 av0, av1;
    short8v pwh0, pwh1, pwl0, pwl1;
    auto ISSUE = [&](int kt) {
        int kc = kt * 64 + as_ * 8;
        const float* p = (kc < 256) ? (x + (size_t)agm * 256 + kc)
                                    : (h + (size_t)agm * 256 + (kc - 256));
        av0 = *(const float4*)p;
        av1 = *(const float4*)(p + 4);
        size_t w0 = (size_t)wrow0 * 512 + kt * 64 + ws_ * 8;
        size_t w1 = (size_t)wrow1 * 512 + kt * 64 + ws_ * 8;
        pwh0 = *(const short8v*)&Whl[w0];
        pwh1 = *(const short8v*)&Whl[w1];
        pwl0 = *(const short8v*)&Whl[65536 + w0];
        pwl1 = *(const short8v*)&Whl[65536 + w1];
    };

    ISSUE(0);
    for (int kt = 0; kt < 8; ++kt) {
        __syncthreads();    // previous compute done; LDS reusable
        {   // cvt + LDS write from regs; side-write Abig hi
            float vv[8] = {av0.x, av0.y, av0.z, av0.w, av1.x, av1.y, av1.z, av1.w};
            short8v hi, lo;
#pragma unroll
            for (int t = 0; t < 8; ++t) {
                unsigned short hb = f2bf(vv[t]);
                hi[t] = (short)hb;
                lo[t] = (short)f2bf(vv[t] - bf2f(hb));
            }
            *(short8v*)&Ah[arow][as_ * 8] = hi;
            *(short8v*)&Al[arow][as_ * 8] = lo;
            *(short8v*)&Abig[(size_t)agm * 640 + kt * 64 + as_ * 8] = hi;
            int p0 = (ws_ ^ (wrow0 & 7)) * 8;
            int p1 = (ws_ ^ (wrow1 & 7)) * 8;
            *(short8v*)&Wh[wrow0 * 64 + p0] = pwh0;
            *(short8v*)&Wl[wrow0 * 64 + p0] = pwl0;
            *(short8v*)&Wh[wrow1 * 64 + p1] = pwh1;
            *(short8v*)&Wl[wrow1 * 64 + p1] = pwl1;
        }
        if (kt < 7) ISSUE(kt + 1);     // global latency hides under MFMAs below
        __syncthreads();
#pragma unroll
        for (int ks = 0; ks < 2; ++ks) {
            int kc = ks * 32 + kg * 8;
            int gsel = (ks * 4 + kg) ^ sw;
            short8v ah[2], al[2], wh[2], wl[2];
#pragma unroll
            for (int f = 0; f < 2; ++f) {
                ah[f] = *(const short8v*)&Ah[wm * 32 + f * 16 + r16][kc];
                al[f] = *(const short8v*)&Al[wm * 32 + f * 16 + r16][kc];
                int wr = wn * 32 + f * 16 + r16;
                wh[f] = *(const short8v*)&Wh[wr * 64 + gsel * 8];
                wl[f] = *(const short8v*)&Wl[wr * 64 + gsel * 8];
            }
#pragma unroll
            for (int fi = 0; fi < 2; ++fi)
#pragma unroll
                for (int fj = 0; fj < 2; ++fj) {
                    acc[fi][fj] = __builtin_amdgcn_mfma_f32_16x16x32_bf16(
                        ah[fi], wh[fj], acc[fi][fj], 0, 0, 0);
                    acc[fi][fj] = __builtin_amdgcn_mfma_f32_16x16x32_bf16(
                        al[fi], wh[fj], acc[fi][fj], 0, 0, 0);
                    acc[fi][fj] = __builtin_amdgcn_mfma_f32_16x16x32_bf16(
                        ah[fi], wl[fj], acc[fi][fj], 0, 0, 0);
                }
        }
    }
    // epilogue: Ldiff via shfl_xor over adjacent columns
#pragma unroll
    for (int fi = 0; fi < 2; ++fi) {
        int rg = bm0 + wm * 32 + fi * 16 + kg * 4;
#pragma unroll
        for (int fj = 0; fj < 2; ++fj) {
            int cg = wn * 32 + fj * 16 + r16;
            float bv = b_enc[cg];
#pragma unroll
            for (int i = 0; i < 4; ++i) {
                float v = acc[fi][fj][i] + bv;
                float o = __shfl_xor(v, 1);
                if (!(r16 & 1) && rg + i < NN)
                    Ldiff[(size_t)(rg + i) * 64 + (cg >> 1)] = v - o;
            }
        }
    }
}

// ---- edge: per-edge gumbel argmax -> OR into cbits (Ldiff form) ----
__global__ __launch_bounds__(256)
void edge_msg_kernel(const float* __restrict__ Ldiff, const float* __restrict__ gumbel,
                     const int* __restrict__ src, const int* __restrict__ dst,
                     unsigned int* __restrict__ cbits, int E)
{
    int lane = threadIdx.x & 63;
    int slot = blockIdx.x * 4 + (threadIdx.x >> 6);
    int nslots = gridDim.x * 4;
    for (int e = slot; e < E; e += nslots) {
        int s = src[e];
        float2 g = *(const float2*)&gumbel[(size_t)e * 128 + lane * 2];
        float d = Ldiff[(size_t)s * 64 + lane];
        int choice1 = (d + g.x) < g.y ? 1 : 0;
        unsigned int val = 1u << (2 * (lane & 15) + choice1);
        val |= __shfl_xor(val, 1);
        val |= __shfl_xor(val, 2);
        val |= __shfl_xor(val, 4);
        val |= __shfl_xor(val, 8);
        if ((lane & 15) == 0) {
            int dn = dst[e];
            atomicOr(&cbits[(size_t)dn * 4 + (lane >> 4)], val);
        }
    }
}

// ---- expand cbits -> Abig[:,512:640] bf16 0/1 ----
__global__ __launch_bounds__(256)
void expand_c(const unsigned int* __restrict__ cbits, unsigned short* __restrict__ Abig)
{
    int idx = blockIdx.x * 256 + threadIdx.x;   // NN*4
    if (idx >= NN * 4) return;
    int n = idx >> 2, w = idx & 3;
    unsigned int bits = cbits[idx];
    unsigned short* p = Abig + (size_t)n * 640 + 512 + w * 32;
#pragma unroll
    for (int t = 0; t < 32; t += 8) {
        short8v v;
#pragma unroll
        for (int u = 0; u < 8; ++u)
            v[u] = ((bits >> (t + u)) & 1u) ? (short)0x3F80 : (short)0;
        *(short8v*)&p[t] = v;
    }
}

// ---- fused gates GEMM + GRU, double-buffered with counted vmcnt ----
__global__ __launch_bounds__(256)
void gates_gru(const unsigned short* __restrict__ Abig,
               const unsigned short* __restrict__ Wbig,
               const float* __restrict__ bias_cat,
               const float* __restrict__ h, float* __restrict__ out)
{
    __shared__ __align__(16) short As[2][64 * 64];    // 2 x 8 KB
    __shared__ __align__(16) short Ws[2][192 * 64];   // 2 x 24 KB
    const int bm0 = blockIdx.x * 64;
    const int j0  = blockIdx.y * 64;
    const int tid = threadIdx.x;
    const int lane = tid & 63;
    const int w = tid >> 6;
    const int r16 = lane & 15, kg = lane >> 4;
    const int sw = r16 & 7;

    f32x4 acc[4][4];
#pragma unroll
    for (int g = 0; g < 4; ++g)
#pragma unroll
        for (int i = 0; i < 4; ++i) acc[g][i] = (f32x4){0.f, 0.f, 0.f, 0.f};

    auto STAGE = [&](int b, int kt) {
        const int kc0 = kt * 64;
        const int g2 = (kt < 4 || kt >= 8) ? 2 : 3;
#pragma unroll
        for (int it = 0; it < 2; ++it) {
            int chunk = w * 2 + it;
            int slot = chunk * 64 + lane;
            int row = slot >> 3, gch = slot & 7;
            int gm = bm0 + row; if (gm >= NN) gm = NN - 1;
            gload16(Abig + (size_t)gm * 640 + kc0 + ((gch ^ (row & 7)) << 3),
                    As[b] + chunk * 512);
        }
#pragma unroll
        for (int it = 0; it < 6; ++it) {
            int chunk = w * 6 + it;
            int slot = chunk * 64 + lane;
            int row = slot >> 3, gch = slot & 7;
            int srow = row >> 6;
            int gate = (srow < 2) ? srow : g2;
            int wr = gate * 256 + j0 + (row & 63);
            gload16(Wbig + (size_t)wr * 640 + kc0 + ((gch ^ (row & 7)) << 3),
                    Ws[b] + chunk * 512);
        }
    };

    STAGE(0, 0);
#pragma unroll
    for (int kt = 0; kt < 10; ++kt) {
        const int cur = kt & 1;
        if (kt < 9) {
            STAGE(cur ^ 1, kt + 1);
            asm volatile("s_waitcnt vmcnt(8)" ::: "memory");
        } else {
            asm volatile("s_waitcnt vmcnt(0)" ::: "memory");
        }
        __builtin_amdgcn_s_barrier();
        __builtin_amdgcn_sched_barrier(0);
        const int g2c = (kt < 4 || kt >= 8) ? 2 : 3;
        __builtin_amdgcn_s_setprio(1);
#pragma unroll
        for (int ks = 0; ks < 2; ++ks) {
            int gsel = (ks * 4 + kg) ^ sw;
            short8v a[4];
#pragma unroll
            for (int fi = 0; fi < 4; ++fi)
                a[fi] = *(const short8v*)&As[cur][(fi * 16 + r16) * 64 + gsel * 8];
#pragma unroll
            for (int s = 0; s < 3; ++s) {
                short8v b = *(const short8v*)&Ws[cur][(s * 64 + w * 16 + r16) * 64 + gsel * 8];
                int gate = (s < 2) ? s : g2c;
#pragma unroll
                for (int fi = 0; fi < 4; ++fi)
                    acc[gate][fi] = __builtin_amdgcn_mfma_f32_16x16x32_bf16(
                        a[fi], b, acc[gate][fi], 0, 0, 0);
            }
        }
        __builtin_amdgcn_s_setprio(0);
        __builtin_amdgcn_sched_barrier(0);
        __builtin_amdgcn_s_barrier();
    }
    const int cg = j0 + w * 16 + r16;
    const float br = bias_cat[cg],       bz = bias_cat[256 + cg];
    const float bi = bias_cat[512 + cg], bh = bias_cat[768 + cg];
#pragma unroll
    for (int fi = 0; fi < 4; ++fi) {
        int rg = bm0 + fi * 16 + kg * 4;
#pragma unroll
        for (int i = 0; i < 4; ++i) {
            int m = rg + i;
            if (m >= NN) continue;
            float rp = acc[0][fi][i] + br;
            float zp = acc[1][fi][i] + bz;
            float ip = acc[2][fi][i] + bi;
            float hp = acc[3][fi][i] + bh;
            float hv = h[(size_t)m * 256 + cg];
            float r = 1.f / (1.f + __expf(-rp));
            float z = 1.f / (1.f + __expf(-zp));
            float nn2 = tanhf(ip + r * hp);
            out[(size_t)m * 256 + cg] = (1.f - z) * nn2 + z * hv;
        }
    }
}

extern "C" void kernel_launch(void* const* d_in, const int* in_sizes, int n_in,
                              void* d_out, int out_size, void* d_ws, size_t ws_size,
                              hipStream_t stream)
{
    const float* x     = (const float*)d_in[0];
    const float* h     = (const float*)d_in[1];
    const float* W_enc = (const float*)d_in[2];
    const float* b_enc = (const float*)d_in[3];
    const float* W_dec = (const float*)d_in[4];
    const float* b_dec = (const float*)d_in[5];
    const float* W_ih  = (const float*)d_in[6];
    const float* b_ih  = (const float*)d_in[7];
    const float* W_hh  = (const float*)d_in[8];
    const float* b_hh  = (const float*)d_in[9];
    const float* gumbel = (const float*)d_in[10];
    const int*   src   = (const int*)d_in[11];
    const int*   dst   = (const int*)d_in[12];
    float* out = (float*)d_out;

    char* ws = (char*)d_ws;
    float*          Ldiff    = (float*)(ws);                      //  5,120,000
    unsigned int*   cbits    = (unsigned int*)(ws + 5120000);     //    320,000
    unsigned short* Wbig     = (unsigned short*)(ws + 5440000);   //  1,310,720
    float*          bias_cat = (float*)(ws + 6750720);            //      4,096
    unsigned short* Whl      = (unsigned short*)(ws + 6754816);   //    262,144
    unsigned short* Abig     = (unsigned short*)(ws + 7016960);   // 25,600,000

    prep_kernel<<<1024, 256, 0, stream>>>(W_ih, W_hh, W_dec, W_enc, b_ih, b_hh, b_dec,
                                          Wbig, bias_cat, cbits, Whl);
    enc_gemm<<<313, 512, 0, stream>>>(x, h, Whl, b_enc, Ldiff, Abig);
    edge_msg_kernel<<<2048, 256, 0, stream>>>(Ldiff, gumbel, src, dst, cbits, NE);
    expand_c<<<(NN * 4 + 255) / 256, 256, 0, stream>>>(cbits, Abig);
    gates_gru<<<dim3(313, 4), 256, 0, stream>>>(Abig, Wbig, bias_cat, h, out);
}

// Round 8
// 199.262 us; speedup vs baseline: 1.2227x; 1.1896x over previous
//
#include <hip/hip_runtime.h>
#include <math.h>

#define NN 20000
#define NE 640000

typedef __attribute__((ext_vector_type(8))) short short8v;
typedef __attribute__((ext_vector_type(4))) float f32x4;

__device__ inline unsigned short f2bf(float f) {
    unsigned int u = __builtin_bit_cast(unsigned int, f);
    u += 0x7fff + ((u >> 16) & 1);   // RNE
    return (unsigned short)(u >> 16);
}
__device__ inline float bf2f(unsigned short s) {
    unsigned int u = ((unsigned int)s) << 16;
    return __builtin_bit_cast(float, u);
}
// async global->LDS, 16B per lane; dest = uniform base + lane*16
__device__ inline void gload16(const unsigned short* g, short* l) {
    __builtin_amdgcn_global_load_lds(
        (const __attribute__((address_space(1))) unsigned int*)g,
        (__attribute__((address_space(3))) unsigned int*)l, 16, 0, 0);
}

// ---- prep: Wbig pack (+W_dec fold), bias_cat, cbits zero, Whl bf16 hi/lo ----
__global__ __launch_bounds__(256)
void prep_kernel(const float* __restrict__ W_ih, const float* __restrict__ W_hh,
                 const float* __restrict__ W_dec, const float* __restrict__ W_enc,
                 const float* __restrict__ b_ih, const float* __restrict__ b_hh,
                 const float* __restrict__ b_dec,
                 unsigned short* __restrict__ Wbig, float* __restrict__ bias_cat,
                 unsigned int* __restrict__ cbits, unsigned short* __restrict__ Whl)
{
    int r = blockIdx.x;              // 1024
    int tid = threadIdx.x;
    int zi = r * 256 + tid;
    if (zi < NN * 4) cbits[zi] = 0u;
    if (r < 128) {                   // Whl: hi/lo planes of W_enc row r
        for (int k2 = tid; k2 < 512; k2 += 256) {
            float v = W_enc[(size_t)r * 512 + k2];
            unsigned short hi = f2bf(v);
            Whl[(size_t)r * 512 + k2] = hi;
            Whl[65536 + (size_t)r * 512 + k2] = f2bf(v - bf2f(hi));
        }
    }
    int g = r >> 8, j = r & 255;
    for (int k = tid; k < 512; k += 256) {
        float v;
        if (k < 256) {
            v = (g < 3) ? W_ih[(size_t)(g * 256 + j) * 384 + k] : 0.f;
        } else {
            int sr = (g < 2) ? g * 256 + j : 512 + j;
            v = (g == 2) ? 0.f : W_hh[(size_t)sr * 256 + (k - 256)];
        }
        Wbig[(size_t)r * 640 + k] = f2bf(v);
    }
    if (tid < 128) {                 // c-cols: (W_ih[:,256:] @ W_dec)[r][tid]
        float acc = 0.f;
        if (g < 3) {
            const float* wr = W_ih + (size_t)(g * 256 + j) * 384 + 256;
#pragma unroll 4
            for (int p = 0; p < 128; ++p) acc += wr[p] * W_dec[p * 128 + tid];
        }
        Wbig[(size_t)r * 640 + 512 + tid] = f2bf(acc);
    } else if (tid == 128) {
        float v;
        if (g == 3) {
            v = b_hh[512 + j];
        } else {
            int sr = g * 256 + j;
            float bdt = 0.f;
            for (int m = 0; m < 128; ++m) bdt += W_ih[(size_t)sr * 384 + 256 + m] * b_dec[m];
            v = b_ih[sr] + bdt + ((g < 2) ? b_hh[sr] : 0.f);
        }
        bias_cat[r] = v;
    }
}

// ---- enc: 8 waves, reg-prefetch pipeline, bf16x3; emits LdiffBf (bf16) + Abig hi ----
__global__ __launch_bounds__(512)
void enc_gemm(const float* __restrict__ x, const float* __restrict__ h,
              const unsigned short* __restrict__ Whl, const float* __restrict__ b_enc,
              unsigned short* __restrict__ LdiffBf, unsigned short* __restrict__ Abig)
{
    __shared__ __align__(16) short Ah[64][72], Al[64][72];
    __shared__ __align__(16) short Wh[128 * 64], Wl[128 * 64];
    const int bm0 = blockIdx.x * 64;
    const int tid = threadIdx.x;       // 0..511
    const int lane = tid & 63;
    const int wave = tid >> 6;
    const int wm = wave >> 2, wn = wave & 3;   // wave: 32 rows x 32 cols
    const int r16 = lane & 15, kg = lane >> 4;
    const int sw = r16 & 7;

    const int arow = tid >> 3, as_ = tid & 7;
    const int agm = (bm0 + arow >= NN) ? NN - 1 : bm0 + arow;
    const int wrow0 = tid >> 3, wrow1 = (tid >> 3) + 64, ws_ = tid & 7;

    f32x4 acc[2][2];
#pragma unroll
    for (int i = 0; i < 2; ++i)
#pragma unroll
        for (int j = 0; j < 2; ++j) acc[i][j] = (f32x4){0.f, 0.f, 0.f, 0.f};

    float4 av0, av1;
    short8v pwh0, pwh1, pwl0, pwl1;
    auto ISSUE = [&](int kt) {
        int kc = kt * 64 + as_ * 8;
        const float* p = (kc < 256) ? (x + (size_t)agm * 256 + kc)
                                    : (h + (size_t)agm * 256 + (kc - 256));
        av0 = *(const float4*)p;
        av1 = *(const float4*)(p + 4);
        size_t w0 = (size_t)wrow0 * 512 + kt * 64 + ws_ * 8;
        size_t w1 = (size_t)wrow1 * 512 + kt * 64 + ws_ * 8;
        pwh0 = *(const short8v*)&Whl[w0];
        pwh1 = *(const short8v*)&Whl[w1];
        pwl0 = *(const short8v*)&Whl[65536 + w0];
        pwl1 = *(const short8v*)&Whl[65536 + w1];
    };

    ISSUE(0);
    for (int kt = 0; kt < 8; ++kt) {
        __syncthreads();
        {
            float vv[8] = {av0.x, av0.y, av0.z, av0.w, av1.x, av1.y, av1.z, av1.w};
            short8v hi, lo;
#pragma unroll
            for (int t = 0; t < 8; ++t) {
                unsigned short hb = f2bf(vv[t]);
                hi[t] = (short)hb;
                lo[t] = (short)f2bf(vv[t] - bf2f(hb));
            }
            *(short8v*)&Ah[arow][as_ * 8] = hi;
            *(short8v*)&Al[arow][as_ * 8] = lo;
            *(short8v*)&Abig[(size_t)agm * 640 + kt * 64 + as_ * 8] = hi;
            int p0 = (ws_ ^ (wrow0 & 7)) * 8;
            int p1 = (ws_ ^ (wrow1 & 7)) * 8;
            *(short8v*)&Wh[wrow0 * 64 + p0] = pwh0;
            *(short8v*)&Wl[wrow0 * 64 + p0] = pwl0;
            *(short8v*)&Wh[wrow1 * 64 + p1] = pwh1;
            *(short8v*)&Wl[wrow1 * 64 + p1] = pwl1;
        }
        if (kt < 7) ISSUE(kt + 1);
        __syncthreads();
#pragma unroll
        for (int ks = 0; ks < 2; ++ks) {
            int kc = ks * 32 + kg * 8;
            int gsel = (ks * 4 + kg) ^ sw;
            short8v ah[2], al[2], wh[2], wl[2];
#pragma unroll
            for (int f = 0; f < 2; ++f) {
                ah[f] = *(const short8v*)&Ah[wm * 32 + f * 16 + r16][kc];
                al[f] = *(const short8v*)&Al[wm * 32 + f * 16 + r16][kc];
                int wr = wn * 32 + f * 16 + r16;
                wh[f] = *(const short8v*)&Wh[wr * 64 + gsel * 8];
                wl[f] = *(const short8v*)&Wl[wr * 64 + gsel * 8];
            }
#pragma unroll
            for (int fi = 0; fi < 2; ++fi)
#pragma unroll
                for (int fj = 0; fj < 2; ++fj) {
                    acc[fi][fj] = __builtin_amdgcn_mfma_f32_16x16x32_bf16(
                        ah[fi], wh[fj], acc[fi][fj], 0, 0, 0);
                    acc[fi][fj] = __builtin_amdgcn_mfma_f32_16x16x32_bf16(
                        al[fi], wh[fj], acc[fi][fj], 0, 0, 0);
                    acc[fi][fj] = __builtin_amdgcn_mfma_f32_16x16x32_bf16(
                        ah[fi], wl[fj], acc[fi][fj], 0, 0, 0);
                }
        }
    }
    // epilogue: Ldiff (bf16) via shfl_xor over adjacent columns
#pragma unroll
    for (int fi = 0; fi < 2; ++fi) {
        int rg = bm0 + wm * 32 + fi * 16 + kg * 4;
#pragma unroll
        for (int fj = 0; fj < 2; ++fj) {
            int cg = wn * 32 + fj * 16 + r16;
            float bv = b_enc[cg];
#pragma unroll
            for (int i = 0; i < 4; ++i) {
                float v = acc[fi][fj][i] + bv;
                float o = __shfl_xor(v, 1);
                if (!(r16 & 1) && rg + i < NN)
                    LdiffBf[(size_t)(rg + i) * 64 + (cg >> 1)] = f2bf(v - o);
            }
        }
    }
}

// ---- edge: 2 edges per wave (32 lanes each), bf16 Ldiff gather ----
__global__ __launch_bounds__(256)
void edge_msg_kernel(const unsigned short* __restrict__ LdiffBf,
                     const float* __restrict__ gumbel,
                     const int* __restrict__ src, const int* __restrict__ dst,
                     unsigned int* __restrict__ cbits, int E)
{
    const int lane = threadIdx.x & 63;
    const int hl = lane & 31;          // lane within half-wave
    const int side = lane >> 5;        // 0 or 1: which edge of the pair
    const int slot = blockIdx.x * 4 + (threadIdx.x >> 6);
    const int nslots = gridDim.x * 4;
    const unsigned int* Lw = (const unsigned int*)LdiffBf;
    for (int p = slot; p * 2 < E; p += nslots) {
        int e = p * 2 + side;
        int s = src[e];
        unsigned int dp = Lw[(size_t)s * 32 + hl];
        float d0 = bf2f((unsigned short)(dp & 0xffffu));
        float d1 = bf2f((unsigned short)(dp >> 16));
        float4 gv = *(const float4*)&gumbel[(size_t)e * 128 + hl * 4];
        int c0 = (d0 + gv.x) < gv.y ? 1 : 0;
        int c1 = (d1 + gv.z) < gv.w ? 1 : 0;
        int sh = (hl & 7) * 4;
        unsigned int val = (1u << (sh + c0)) | (1u << (sh + 2 + c1));
        val |= __shfl_xor(val, 1);
        val |= __shfl_xor(val, 2);
        val |= __shfl_xor(val, 4);
        if ((hl & 7) == 0) {
            int dn = dst[e];
            atomicOr(&cbits[(size_t)dn * 4 + (hl >> 3)], val);
        }
    }
}

// ---- expand cbits -> Abig[:,512:640] bf16 0/1 ----
__global__ __launch_bounds__(256)
void expand_c(const unsigned int* __restrict__ cbits, unsigned short* __restrict__ Abig)
{
    int idx = blockIdx.x * 256 + threadIdx.x;   // NN*4
    if (idx >= NN * 4) return;
    int n = idx >> 2, w = idx & 3;
    unsigned int bits = cbits[idx];
    unsigned short* p = Abig + (size_t)n * 640 + 512 + w * 32;
#pragma unroll
    for (int t = 0; t < 32; t += 8) {
        short8v v;
#pragma unroll
        for (int u = 0; u < 8; ++u)
            v[u] = ((bits >> (t + u)) & 1u) ? (short)0x3F80 : (short)0;
        *(short8v*)&p[t] = v;
    }
}

// ---- fused gates GEMM + GRU: A via dbuf LDS (gload16), B streamed to regs ----
// Block: 64 rows x 64 hidden cols; wave w: cols [16w,16w+16), all 4 gates.
// K layout [x(0:256)|h(256:512)|c(512:640)]; 3 active gate slabs per kt.
__global__ __launch_bounds__(256)
void gates_gru(const unsigned short* __restrict__ Abig,
               const unsigned short* __restrict__ Wbig,
               const float* __restrict__ bias_cat,
               const float* __restrict__ h, float* __restrict__ out)
{
    __shared__ __align__(16) short As[2][64 * 64];    // 2 x 8 KB
    const int bm0 = blockIdx.x * 64;
    const int j0  = blockIdx.y * 64;
    const int tid = threadIdx.x;
    const int lane = tid & 63;
    const int w = tid >> 6;
    const int r16 = lane & 15, kg = lane >> 4;
    const int sw = r16 & 7;

    f32x4 acc[4][4];
#pragma unroll
    for (int g = 0; g < 4; ++g)
#pragma unroll
        for (int i = 0; i < 4; ++i) acc[g][i] = (f32x4){0.f, 0.f, 0.f, 0.f};

    // A staging: 2 gload16 per wave per kt
    auto STAGE = [&](int b, int kt) {
        const int kc0 = kt * 64;
#pragma unroll
        for (int it = 0; it < 2; ++it) {
            int chunk = w * 2 + it;
            int slot = chunk * 64 + lane;
            int row = slot >> 3, gch = slot & 7;
            int gm = bm0 + row; if (gm >= NN) gm = NN - 1;
            gload16(Abig + (size_t)gm * 640 + kc0 + ((gch ^ (row & 7)) << 3),
                    As[b] + chunk * 512);
        }
    };
    // B: 6 register loads per wave per kt (L2-resident Wbig)
    short8v breg[2][3][2];
    auto BLOAD = [&](int b, int kt) {
        const int kc0 = kt * 64;
        const int g2 = (kt < 4 || kt >= 8) ? 2 : 3;
#pragma unroll
        for (int s = 0; s < 3; ++s) {
            int gate = (s < 2) ? s : g2;
            const unsigned short* bp =
                Wbig + (size_t)(gate * 256 + j0 + w * 16 + r16) * 640 + kc0 + kg * 8;
            breg[b][s][0] = *(const short8v*)bp;
            breg[b][s][1] = *(const short8v*)(bp + 32);
        }
    };

    STAGE(0, 0);
    BLOAD(0, 0);
#pragma unroll
    for (int kt = 0; kt < 10; ++kt) {
        const int cur = kt & 1;
        if (kt < 9) {
            STAGE(cur ^ 1, kt + 1);
            BLOAD(cur ^ 1, kt + 1);
            asm volatile("s_waitcnt vmcnt(8)" ::: "memory");
        } else {
            asm volatile("s_waitcnt vmcnt(0)" ::: "memory");
        }
        __builtin_amdgcn_s_barrier();
        __builtin_amdgcn_sched_barrier(0);
        const int g2c = (kt < 4 || kt >= 8) ? 2 : 3;
        __builtin_amdgcn_s_setprio(1);
#pragma unroll
        for (int ks = 0; ks < 2; ++ks) {
            int gsel = (ks * 4 + kg) ^ sw;
            short8v a[4];
#pragma unroll
            for (int fi = 0; fi < 4; ++fi)
                a[fi] = *(const short8v*)&As[cur][(fi * 16 + r16) * 64 + gsel * 8];
#pragma unroll
            for (int s = 0; s < 3; ++s) {
                int gate = (s < 2) ? s : g2c;
#pragma unroll
                for (int fi = 0; fi < 4; ++fi)
                    acc[gate][fi] = __builtin_amdgcn_mfma_f32_16x16x32_bf16(
                        a[fi], breg[cur][s][ks], acc[gate][fi], 0, 0, 0);
            }
        }
        __builtin_amdgcn_s_setprio(0);
        __builtin_amdgcn_sched_barrier(0);
        __builtin_amdgcn_s_barrier();
    }
    const int cg = j0 + w * 16 + r16;
    const float br = bias_cat[cg],       bz = bias_cat[256 + cg];
    const float bi = bias_cat[512 + cg], bh = bias_cat[768 + cg];
#pragma unroll
    for (int fi = 0; fi < 4; ++fi) {
        int rg = bm0 + fi * 16 + kg * 4;
#pragma unroll
        for (int i = 0; i < 4; ++i) {
            int m = rg + i;
            if (m >= NN) continue;
            float rp = acc[0][fi][i] + br;
            float zp = acc[1][fi][i] + bz;
            float ip = acc[2][fi][i] + bi;
            float hp = acc[3][fi][i] + bh;
            float hv = h[(size_t)m * 256 + cg];
            float r = 1.f / (1.f + __expf(-rp));
            float z = 1.f / (1.f + __expf(-zp));
            float nn2 = tanhf(ip + r * hp);
            out[(size_t)m * 256 + cg] = (1.f - z) * nn2 + z * hv;
        }
    }
}

extern "C" void kernel_launch(void* const* d_in, const int* in_sizes, int n_in,
                              void* d_out, int out_size, void* d_ws, size_t ws_size,
                              hipStream_t stream)
{
    const float* x     = (const float*)d_in[0];
    const float* h     = (const float*)d_in[1];
    const float* W_enc = (const float*)d_in[2];
    const float* b_enc = (const float*)d_in[3];
    const float* W_dec = (const float*)d_in[4];
    const float* b_dec = (const float*)d_in[5];
    const float* W_ih  = (const float*)d_in[6];
    const float* b_ih  = (const float*)d_in[7];
    const float* W_hh  = (const float*)d_in[8];
    const float* b_hh  = (const float*)d_in[9];
    const float* gumbel = (const float*)d_in[10];
    const int*   src   = (const int*)d_in[11];
    const int*   dst   = (const int*)d_in[12];
    float* out = (float*)d_out;

    char* ws = (char*)d_ws;
    unsigned short* LdiffBf  = (unsigned short*)(ws);             //  2,560,000
    unsigned int*   cbits    = (unsigned int*)(ws + 2560000);     //    320,000
    unsigned short* Wbig     = (unsigned short*)(ws + 2880000);   //  1,310,720
    float*          bias_cat = (float*)(ws + 4190720);            //      4,096
    unsigned short* Whl      = (unsigned short*)(ws + 4194816);   //    262,144
    unsigned short* Abig     = (unsigned short*)(ws + 4456960);   // 25,600,000

    prep_kernel<<<1024, 256, 0, stream>>>(W_ih, W_hh, W_dec, W_enc, b_ih, b_hh, b_dec,
                                          Wbig, bias_cat, cbits, Whl);
    enc_gemm<<<313, 512, 0, stream>>>(x, h, Whl, b_enc, LdiffBf, Abig);
    edge_msg_kernel<<<2048, 256, 0, stream>>>(LdiffBf, gumbel, src, dst, cbits, NE);
    expand_c<<<(NN * 4 + 255) / 256, 256, 0, stream>>>(cbits, Abig);
    gates_gru<<<dim3(313, 4), 256, 0, stream>>>(Abig, Wbig, bias_cat, h, out);
}